// Round 7
// baseline (1619.491 us; speedup 1.0000x reference)
//
#include <hip/hip_runtime.h>

#define NN 100000
#define EE 1600000
#define HD 64
#define OCD 16
#define NS 4      // feature slices
#define SW 16     // slice width
#define PB 25000  // prop blocks per pass (NN/4)
#define BN_EPS 1e-5f

typedef unsigned short u16;
typedef unsigned long long u64;

union f32u32 { float f; unsigned int u; };

__device__ __forceinline__ float bflo(unsigned int u) {
    f32u32 c; c.u = u << 16; return c.f;
}
__device__ __forceinline__ float bfhi(unsigned int u) {
    f32u32 c; c.u = u & 0xffff0000u; return c.f;
}
__device__ __forceinline__ u16 f2bf(float f) {
    f32u32 c; c.f = f;
    unsigned int r = 0x7fffu + ((c.u >> 16) & 1u);   // RNE
    return (u16)((c.u + r) >> 16);
}

// ================================================================ CSR build
__global__ void hist_kernel(const int* __restrict__ src, const int* __restrict__ dst,
                            int* __restrict__ cs, int* __restrict__ cd) {
    int e = blockIdx.x * 256 + threadIdx.x;
    if (e < EE) {
        atomicAdd(&cs[src[e]], 1);
        atomicAdd(&cd[dst[e]], 1);
    }
}

__global__ void dinv_kernel(const int* __restrict__ cs, float* __restrict__ dinv,
                            float* __restrict__ ndsq, float* __restrict__ sdeg) {
    int i = blockIdx.x * 256 + threadIdx.x;
    if (i < NN) {
        int d = cs[i];
        float di = (d > 0) ? rsqrtf((float)d) : 0.0f;
        dinv[i] = di;
        ndsq[i] = -di * di;
        sdeg[i] = (d > 0) ? sqrtf((float)d) : 0.0f;
    }
}

__global__ __launch_bounds__(256) void scan1_kernel(const int* __restrict__ cd,
                                                    int* __restrict__ bsum) {
    __shared__ int ws[4];
    int base = blockIdx.x * 1024;
    int t = threadIdx.x;
    int s = 0;
    #pragma unroll
    for (int j = 0; j < 4; ++j) {
        int i = base + t * 4 + j;
        if (i < NN) s += cd[i];
    }
    #pragma unroll
    for (int o = 32; o > 0; o >>= 1) s += __shfl_down(s, o);
    if ((t & 63) == 0) ws[t >> 6] = s;
    __syncthreads();
    if (t == 0) bsum[blockIdx.x] = ws[0] + ws[1] + ws[2] + ws[3];
}

__global__ void scan2_kernel(int* bsum, int nb, int* rowp) {
    if (threadIdx.x == 0 && blockIdx.x == 0) {
        int run = 0;
        for (int b = 0; b < nb; ++b) { int v = bsum[b]; bsum[b] = run; run += v; }
        rowp[NN] = run;
    }
}

__global__ __launch_bounds__(256) void scan3_kernel(const int* __restrict__ cd,
                                                    const int* __restrict__ bsum,
                                                    int* __restrict__ rowp,
                                                    int* __restrict__ cursor) {
    __shared__ int tsum[256];
    int base = blockIdx.x * 1024;
    int t = threadIdx.x;
    int v[4]; int s = 0;
    #pragma unroll
    for (int j = 0; j < 4; ++j) {
        int i = base + t * 4 + j;
        v[j] = (i < NN) ? cd[i] : 0;
        s += v[j];
    }
    tsum[t] = s;
    __syncthreads();
    for (int o = 1; o < 256; o <<= 1) {
        int xv = (t >= o) ? tsum[t - o] : 0;
        __syncthreads();
        tsum[t] += xv;
        __syncthreads();
    }
    int excl = bsum[blockIdx.x] + tsum[t] - s;
    #pragma unroll
    for (int j = 0; j < 4; ++j) {
        int i = base + t * 4 + j;
        if (i < NN) { rowp[i] = excl; cursor[i] = excl; excl += v[j]; }
    }
}

__global__ void scatter_kernel(const int* __restrict__ src, const int* __restrict__ dst,
                               int* __restrict__ cursor, int* __restrict__ col) {
    int e = blockIdx.x * 256 + threadIdx.x;
    if (e >= EE) return;
    int pos = atomicAdd(&cursor[dst[e]], 1);
    col[pos] = src[e];
}

// ================================================================ weight folding
__global__ void fold_kernel(const float* __restrict__ W, const float* __restrict__ bc,
                            const float* __restrict__ g, const float* __restrict__ be,
                            const float* __restrict__ rm, const float* __restrict__ rv,
                            float* __restrict__ Wf, float* __restrict__ biasf) {
    int idx = blockIdx.x * 256 + threadIdx.x;
    if (idx >= 4096) return;
    int h = idx & 63;
    float sc = g[h] * rsqrtf(rv[h] + BN_EPS);
    float w0 = W[idx], w1 = W[4096 + idx], w2 = W[8192 + idx], w3 = W[12288 + idx];
    Wf[idx]         = (w0 - w2) * sc;
    Wf[4096 + idx]  = (w1 - 3.0f * w3) * sc;
    Wf[8192 + idx]  = (2.0f * w2) * sc;
    Wf[12288 + idx] = (4.0f * w3) * sc;
    if (idx < 64)
        biasf[idx] = (bc[idx] - rm[idx]) * g[idx] * rsqrtf(rv[idx] + BN_EPS) + be[idx];
}

// ================================================================ P0 = bf16(dinv * x), sliced layout [NS][NN][SW]
__global__ void scale0_kernel(const float* __restrict__ x, const float* __restrict__ dinv,
                              u16* __restrict__ P0) {
    int idx = blockIdx.x * 256 + threadIdx.x;   // slice-major: s = idx/NN
    if (idx >= NS * NN) return;
    int s = idx / NN, n = idx - s * NN;
    float di = dinv[n];
    const float4* xr = (const float4*)(x + (size_t)n * HD + s * SW);
    float4 v0 = xr[0], v1 = xr[1], v2 = xr[2], v3 = xr[3];
    u16 o[16] = {
        f2bf(di * v0.x), f2bf(di * v0.y), f2bf(di * v0.z), f2bf(di * v0.w),
        f2bf(di * v1.x), f2bf(di * v1.y), f2bf(di * v1.z), f2bf(di * v1.w),
        f2bf(di * v2.x), f2bf(di * v2.y), f2bf(di * v2.z), f2bf(di * v2.w),
        f2bf(di * v3.x), f2bf(di * v3.y), f2bf(di * v3.z), f2bf(di * v3.w)
    };
    uint4* dp = (uint4*)(P0 + (size_t)s * (NN * SW) + (size_t)n * SW);
    dp[0] = ((const uint4*)o)[0];
    dp[1] = ((const uint4*)o)[1];
}

// ================================================================ propagation (L2-resident slice)
// P_{k+1}[d][f] = -dinv[d]^2 * sum_{s in row(d)} P_k[s][f], one 16-feature slice per pass.
// Wave = 16 edge-groups x 4 lanes; one load gathers 16 distinct 32B rows.
__global__ __launch_bounds__(256) void prop_kernel(
        const u16* __restrict__ Pin, u16* __restrict__ Pout,
        const int* __restrict__ rowp, const int* __restrict__ col,
        const float* __restrict__ ndsq) {
    int bid = blockIdx.x;
    int pass = bid / PB;                       // slice index, pass-major dispatch
    int d = (bid - pass * PB) * 4 + (threadIdx.x >> 6);
    int lane = threadIdx.x & 63;
    int g = lane >> 2;       // 0..15 edge slot
    int l = lane & 3;        // feature quad within slice
    const u16* Ps = Pin + (size_t)pass * (NN * SW);
    u16* Pd = Pout + (size_t)pass * (NN * SW);
    int e0 = rowp[d], e1 = rowp[d + 1];

    float a0 = 0.f, a1 = 0.f, a2 = 0.f, a3 = 0.f;
    for (int e = e0 + g; e < e1; e += 16) {
        int s = __builtin_nontemporal_load(col + e);
        uint2 u = *(const uint2*)(Ps + (size_t)s * SW + l * 4);
        a0 += bflo(u.x); a1 += bfhi(u.x);
        a2 += bflo(u.y); a3 += bfhi(u.y);
    }
    #pragma unroll
    for (int m = 4; m <= 32; m <<= 1) {
        a0 += __shfl_xor(a0, m);
        a1 += __shfl_xor(a1, m);
        a2 += __shfl_xor(a2, m);
        a3 += __shfl_xor(a3, m);
    }
    if (g == 0) {
        float nd = ndsq[d];
        u64 o = (u64)((unsigned int)f2bf(nd * a0) | ((unsigned int)f2bf(nd * a1) << 16))
              | ((u64)((unsigned int)f2bf(nd * a2) | ((unsigned int)f2bf(nd * a3) << 16)) << 32);
        __builtin_nontemporal_store(o, (u64*)(Pd + (size_t)d * SW + l * 4));
    }
}

// ================================================================ combine
template<bool FUSE_HEAD>
__global__ __launch_bounds__(256, 4) void combine_kernel(
        const float* __restrict__ X,      // N x 64 fp32 (T0)
        const u16* __restrict__ P1, const u16* __restrict__ P2,
        const u16* __restrict__ P3,      // sliced [NS][NN][SW]
        const float* __restrict__ sdeg, const float* __restrict__ dinv,
        const float* __restrict__ Wf, const float* __restrict__ biasf,
        float* __restrict__ outh, u16* __restrict__ outP,
        const float* __restrict__ headW, const float* __restrict__ headB,
        float* __restrict__ out16) {
    __shared__ float Tl[64][68];   // +4 pad
    __shared__ float Wl[4096];

    int nbase = blockIdx.x * 64;
    int t = threadIdx.x;
    int h0 = (t & 15) * 4;
    int n0 = (t >> 4) * 4;

    float acc[4][4] = {{0.f}};
    const u16* Ps[3] = {P1, P2, P3};

    for (int k = 0; k < 4; ++k) {
        __syncthreads();   // protect previous iteration's LDS reads
        const float* Wk = Wf + k * 4096;
        #pragma unroll
        for (int j = 0; j < 4; ++j)
            ((float4*)Wl)[t + j * 256] = ((const float4*)Wk)[t + j * 256];

        if (k == 0) {
            const float* Tk = X + (size_t)nbase * HD;
            #pragma unroll
            for (int jj = 0; jj < 4; ++jj) {
                int j = t + jj * 256;
                int r = j >> 4, c = (j & 15) * 4;
                float4 tv = make_float4(0.f, 0.f, 0.f, 0.f);
                if (nbase + r < NN) tv = *(const float4*)(Tk + r * HD + c);
                *(float4*)(&Tl[r][c]) = tv;
            }
        } else {
            const u16* Pk = Ps[k - 1];
            int r = t & 63, s = t >> 6;          // 64 rows x 4 slices
            int n = nbase + r;
            uint4 ua = make_uint4(0, 0, 0, 0), ub = make_uint4(0, 0, 0, 0);
            float sd = 0.f;
            if (n < NN) {
                const uint4* bp = (const uint4*)(Pk + (size_t)s * (NN * SW) + (size_t)n * SW);
                ua = bp[0]; ub = bp[1];
                sd = sdeg[n];
            }
            float* tr = &Tl[r][s * SW];
            tr[0]  = sd * bflo(ua.x); tr[1]  = sd * bfhi(ua.x);
            tr[2]  = sd * bflo(ua.y); tr[3]  = sd * bfhi(ua.y);
            tr[4]  = sd * bflo(ua.z); tr[5]  = sd * bfhi(ua.z);
            tr[6]  = sd * bflo(ua.w); tr[7]  = sd * bfhi(ua.w);
            tr[8]  = sd * bflo(ub.x); tr[9]  = sd * bfhi(ub.x);
            tr[10] = sd * bflo(ub.y); tr[11] = sd * bfhi(ub.y);
            tr[12] = sd * bflo(ub.z); tr[13] = sd * bfhi(ub.z);
            tr[14] = sd * bflo(ub.w); tr[15] = sd * bfhi(ub.w);
        }
        __syncthreads();

        #pragma unroll 4
        for (int i0 = 0; i0 < 64; i0 += 4) {
            float av[4][4], bv[4][4];
            #pragma unroll
            for (int j = 0; j < 4; ++j) {
                float4 a = *(const float4*)(&Tl[n0 + j][i0]);
                av[j][0] = a.x; av[j][1] = a.y; av[j][2] = a.z; av[j][3] = a.w;
            }
            #pragma unroll
            for (int p = 0; p < 4; ++p) {
                float4 b = *(const float4*)(&Wl[(i0 + p) * 64 + h0]);
                bv[p][0] = b.x; bv[p][1] = b.y; bv[p][2] = b.z; bv[p][3] = b.w;
            }
            #pragma unroll
            for (int j = 0; j < 4; ++j)
                #pragma unroll
                for (int q = 0; q < 4; ++q)
                    #pragma unroll
                    for (int p = 0; p < 4; ++p)
                        acc[j][q] = fmaf(av[j][p], bv[p][q], acc[j][q]);
        }
    }

    float bih[4];
    #pragma unroll
    for (int q = 0; q < 4; ++q) bih[q] = biasf[h0 + q];

    if (!FUSE_HEAD) {
        int sl = h0 >> 4, soff = h0 & 15;    // outP slice coords
        #pragma unroll
        for (int j = 0; j < 4; ++j) {
            int n = nbase + n0 + j;
            if (n >= NN) continue;
            float4 o;
            o.x = fmaxf(acc[j][0] + bih[0], 0.f);
            o.y = fmaxf(acc[j][1] + bih[1], 0.f);
            o.z = fmaxf(acc[j][2] + bih[2], 0.f);
            o.w = fmaxf(acc[j][3] + bih[3], 0.f);
            *(float4*)(&outh[(size_t)n * HD + h0]) = o;
            float di = dinv[n];
            u64 op = (u64)((unsigned int)f2bf(di * o.x) | ((unsigned int)f2bf(di * o.y) << 16))
                   | ((u64)((unsigned int)f2bf(di * o.z) | ((unsigned int)f2bf(di * o.w) << 16)) << 32);
            *(u64*)(outP + (size_t)sl * (NN * SW) + (size_t)n * SW + soff) = op;
        }
    } else {
        __syncthreads();   // done reading Tl for k=3
        #pragma unroll
        for (int j = 0; j < 4; ++j) {
            float4 o;
            o.x = fmaxf(acc[j][0] + bih[0], 0.f);
            o.y = fmaxf(acc[j][1] + bih[1], 0.f);
            o.z = fmaxf(acc[j][2] + bih[2], 0.f);
            o.w = fmaxf(acc[j][3] + bih[3], 0.f);
            *(float4*)(&Tl[n0 + j][h0]) = o;
        }
        ((float4*)Wl)[t] = ((const float4*)headW)[t & 255];  // 64x16 = 256 float4
        __syncthreads();

        int n = t >> 2;
        int oc0 = (t & 3) * 4;
        float4 o;
        o.x = headB[oc0]; o.y = headB[oc0 + 1]; o.z = headB[oc0 + 2]; o.w = headB[oc0 + 3];
        #pragma unroll 8
        for (int i = 0; i < 64; ++i) {
            float tv = Tl[n][i];
            const float* wr = &Wl[i * OCD + oc0];
            o.x = fmaf(tv, wr[0], o.x);
            o.y = fmaf(tv, wr[1], o.y);
            o.z = fmaf(tv, wr[2], o.z);
            o.w = fmaf(tv, wr[3], o.w);
        }
        int nn = nbase + n;
        if (nn < NN) *(float4*)(&out16[(size_t)nn * OCD + oc0]) = o;
    }
}

// ================================================================ launch
static inline size_t al256(size_t x) { return (x + 255) & ~(size_t)255; }

extern "C" void kernel_launch(void* const* d_in, const int* in_sizes, int n_in,
                              void* d_out, int out_size, void* d_ws, size_t ws_size,
                              hipStream_t stream) {
    const float* x     = (const float*)d_in[0];
    const int*   ei    = (const int*)  d_in[1];
    const float* W1    = (const float*)d_in[2];
    const float* bc1   = (const float*)d_in[3];
    const float* W2    = (const float*)d_in[4];
    const float* bc2   = (const float*)d_in[5];
    const float* W3    = (const float*)d_in[6];
    const float* bc3   = (const float*)d_in[7];
    const float* g1  = (const float*)d_in[8],  *be1 = (const float*)d_in[9];
    const float* rm1 = (const float*)d_in[10], *rv1 = (const float*)d_in[11];
    const float* g2  = (const float*)d_in[12], *be2 = (const float*)d_in[13];
    const float* rm2 = (const float*)d_in[14], *rv2 = (const float*)d_in[15];
    const float* g3  = (const float*)d_in[16], *be3 = (const float*)d_in[17];
    const float* rm3 = (const float*)d_in[18], *rv3 = (const float*)d_in[19];
    const float* headW = (const float*)d_in[20];
    const float* headB = (const float*)d_in[21];

    const int* src = ei;
    const int* dst = ei + EE;

    char* w = (char*)d_ws;
    size_t off = 0;
    auto take = [&](size_t bytes) { char* p = w + off; off += al256(bytes); return p; };
    float* dinv   = (float*)take(NN * 4);
    float* ndsq   = (float*)take(NN * 4);
    float* sdeg   = (float*)take(NN * 4);
    int*   cs     = (int*)  take(NN * 4);
    int*   cd     = (int*)  take(NN * 4);
    int*   rowp   = (int*)  take((NN + 1) * 4);
    int*   cursor = (int*)  take(NN * 4);
    int*   bsum   = (int*)  take(256 * 4);
    int*   col    = (int*)  take((size_t)EE * 4);
    float* Wf1    = (float*)take(16384 * 4);
    float* Wf2    = (float*)take(16384 * 4);
    float* Wf3    = (float*)take(16384 * 4);
    float* bf1    = (float*)take(64 * 4);
    float* bf2    = (float*)take(64 * 4);
    float* bf3    = (float*)take(64 * 4);
    const size_t NH = (size_t)NN * HD;
    u16* P0 = (u16*)take(NH * 2);
    u16* P1 = (u16*)take(NH * 2);
    u16* P2 = (u16*)take(NH * 2);
    u16* P3 = (u16*)take(NH * 2);
    float* D = (float*)take(NH * 4);

    const int NB_SCAN = (NN + 1023) / 1024;
    const int EG = (EE + 255) / 256;
    const int NG = (NN + 255) / 256;
    const int PROP_GRID = NS * PB;              // pass-major
    const int CB_GRID   = (NN + 63) / 64;
    const int S0_GRID   = (NS * NN + 255) / 256;

    // ---- CSR build + folding
    hipMemsetAsync(cs, 0, NN * 4, stream);
    hipMemsetAsync(cd, 0, NN * 4, stream);
    hist_kernel<<<EG, 256, 0, stream>>>(src, dst, cs, cd);
    dinv_kernel<<<NG, 256, 0, stream>>>(cs, dinv, ndsq, sdeg);
    scan1_kernel<<<NB_SCAN, 256, 0, stream>>>(cd, bsum);
    scan2_kernel<<<1, 64, 0, stream>>>(bsum, NB_SCAN, rowp);
    scan3_kernel<<<NB_SCAN, 256, 0, stream>>>(cd, bsum, rowp, cursor);
    scatter_kernel<<<EG, 256, 0, stream>>>(src, dst, cursor, col);
    fold_kernel<<<16, 256, 0, stream>>>(W1, bc1, g1, be1, rm1, rv1, Wf1, bf1);
    fold_kernel<<<16, 256, 0, stream>>>(W2, bc2, g2, be2, rm2, rv2, Wf2, bf2);
    fold_kernel<<<16, 256, 0, stream>>>(W3, bc3, g3, be3, rm3, rv3, Wf3, bf3);
    scale0_kernel<<<S0_GRID, 256, 0, stream>>>(x, dinv, P0);

    float* out16 = (float*)d_out;

    // ---- layer 1
    prop_kernel<<<PROP_GRID, 256, 0, stream>>>(P0, P1, rowp, col, ndsq);
    prop_kernel<<<PROP_GRID, 256, 0, stream>>>(P1, P2, rowp, col, ndsq);
    prop_kernel<<<PROP_GRID, 256, 0, stream>>>(P2, P3, rowp, col, ndsq);
    combine_kernel<false><<<CB_GRID, 256, 0, stream>>>(x, P1, P2, P3, sdeg, dinv,
                                                       Wf1, bf1, D, P0,
                                                       nullptr, nullptr, nullptr);
    // ---- layer 2
    prop_kernel<<<PROP_GRID, 256, 0, stream>>>(P0, P1, rowp, col, ndsq);
    prop_kernel<<<PROP_GRID, 256, 0, stream>>>(P1, P2, rowp, col, ndsq);
    prop_kernel<<<PROP_GRID, 256, 0, stream>>>(P2, P3, rowp, col, ndsq);
    combine_kernel<false><<<CB_GRID, 256, 0, stream>>>(D, P1, P2, P3, sdeg, dinv,
                                                       Wf2, bf2, D, P0,
                                                       nullptr, nullptr, nullptr);
    // ---- layer 3 (head fused)
    prop_kernel<<<PROP_GRID, 256, 0, stream>>>(P0, P1, rowp, col, ndsq);
    prop_kernel<<<PROP_GRID, 256, 0, stream>>>(P1, P2, rowp, col, ndsq);
    prop_kernel<<<PROP_GRID, 256, 0, stream>>>(P2, P3, rowp, col, ndsq);
    combine_kernel<true><<<CB_GRID, 256, 0, stream>>>(D, P1, P2, P3, sdeg, dinv,
                                                      Wf3, bf3, nullptr, nullptr,
                                                      headW, headB, out16);
}

// Round 9
// 672.234 us; speedup vs baseline: 2.4091x; 2.4091x over previous
//
#include <hip/hip_runtime.h>

#define NN 100000
#define EE 1600000
#define HD 64
#define OCD 16
#define NBUCK 391          // ceil(NN/256)
#define CAP 5120           // per-bucket edge capacity (mean 4096, ~16 sigma margin)
#define BN_EPS 1e-5f

typedef unsigned short u16;
typedef unsigned long long u64;

union f32u32 { float f; unsigned int u; };

__device__ __forceinline__ float bflo(unsigned int u) {
    f32u32 c; c.u = u << 16; return c.f;
}
__device__ __forceinline__ float bfhi(unsigned int u) {
    f32u32 c; c.u = u & 0xffff0000u; return c.f;
}
__device__ __forceinline__ u16 f2bf(float f) {
    f32u32 c; c.f = f;
    unsigned int r = 0x7fffu + ((c.u >> 16) & 1u);   // RNE
    return (u16)((c.u + r) >> 16);
}

// ================================================================ bucket pass A: edges -> dst-bucket regions
__global__ __launch_bounds__(256) void bucketA_kernel(
        const int* __restrict__ src, const int* __restrict__ dst,
        int* __restrict__ gcd,          // per-bucket cursors, stride 16 ints
        u64* __restrict__ bregion) {    // [NBUCK][CAP] packed (src | dst<<32)
    __shared__ int lh[NBUCK], lbase[NBUCK], lcur[NBUCK];
    int t = threadIdx.x;
    int ebase = blockIdx.x * 4096;

    for (int i = t; i < NBUCK; i += 256) lh[i] = 0;
    __syncthreads();

    int es[16], ed[16];
    #pragma unroll
    for (int j = 0; j < 16; ++j) {
        int e = ebase + j * 256 + t;
        if (e < EE) {
            es[j] = src[e]; ed[j] = dst[e];
            atomicAdd(&lh[ed[j] >> 8], 1);
        } else { es[j] = -1; ed[j] = 0; }
    }
    __syncthreads();
    for (int i = t; i < NBUCK; i += 256) {
        int c = lh[i];
        lbase[i] = (c > 0) ? atomicAdd(&gcd[i * 16], c) : 0;
        lcur[i] = 0;
    }
    __syncthreads();
    #pragma unroll
    for (int j = 0; j < 16; ++j) {
        if (es[j] >= 0) {
            int b = ed[j] >> 8;
            int r = atomicAdd(&lcur[b], 1);
            int pos = lbase[b] + r;
            if (pos < CAP)
                bregion[(size_t)b * CAP + pos] =
                    (u64)(unsigned int)es[j] | ((u64)(unsigned int)ed[j] << 32);
        }
    }
}

// same but keyed by src, payload = src only (for out-degree counts)
__global__ __launch_bounds__(256) void bucketA2_kernel(
        const int* __restrict__ src,
        int* __restrict__ gcs, int* __restrict__ sregion) {
    __shared__ int lh[NBUCK], lbase[NBUCK], lcur[NBUCK];
    int t = threadIdx.x;
    int ebase = blockIdx.x * 4096;

    for (int i = t; i < NBUCK; i += 256) lh[i] = 0;
    __syncthreads();

    int es[16];
    #pragma unroll
    for (int j = 0; j < 16; ++j) {
        int e = ebase + j * 256 + t;
        if (e < EE) {
            es[j] = src[e];
            atomicAdd(&lh[es[j] >> 8], 1);
        } else es[j] = -1;
    }
    __syncthreads();
    for (int i = t; i < NBUCK; i += 256) {
        int c = lh[i];
        lbase[i] = (c > 0) ? atomicAdd(&gcs[i * 16], c) : 0;
        lcur[i] = 0;
    }
    __syncthreads();
    #pragma unroll
    for (int j = 0; j < 16; ++j) {
        if (es[j] >= 0) {
            int b = es[j] >> 8;
            int r = atomicAdd(&lcur[b], 1);
            int pos = lbase[b] + r;
            if (pos < CAP)
                sregion[(size_t)b * CAP + pos] = es[j];
        }
    }
}

// ================================================================ pass B: per dst-bucket CSR
__global__ __launch_bounds__(256) void bucketB_kernel(
        const int* __restrict__ gcd, const u64* __restrict__ bregion,
        int* __restrict__ rstart, int* __restrict__ deg,
        int* __restrict__ colp) {
    __shared__ int lh[256], lsc[256], lcur[256];
    int b = blockIdx.x, t = threadIdx.x;
    int cnt = min(gcd[b * 16], CAP);
    size_t base = (size_t)b * CAP;

    lh[t] = 0;
    __syncthreads();
    for (int i = t; i < cnt; i += 256) {
        int d = (int)(bregion[base + i] >> 32);
        atomicAdd(&lh[d & 255], 1);
    }
    __syncthreads();
    lsc[t] = lh[t];
    __syncthreads();
    for (int o = 1; o < 256; o <<= 1) {
        int v = (t >= o) ? lsc[t - o] : 0;
        __syncthreads();
        lsc[t] += v;
        __syncthreads();
    }
    int excl = lsc[t] - lh[t];
    int node = b * 256 + t;
    if (node < NN) {
        rstart[node] = (int)base + excl;
        deg[node] = lh[t];
    }
    lcur[t] = excl;
    __syncthreads();
    for (int i = t; i < cnt; i += 256) {
        u64 pair = bregion[base + i];
        int s = (int)(unsigned int)(pair & 0xffffffffu);
        int dl = ((int)(pair >> 32)) & 255;
        int p = atomicAdd(&lcur[dl], 1);
        colp[base + p] = s;
    }
}

// per src-bucket: out-degree counts -> cs
__global__ __launch_bounds__(256) void bucketB2_kernel(
        const int* __restrict__ gcs, const int* __restrict__ sregion,
        int* __restrict__ cs) {
    __shared__ int lh[256];
    int b = blockIdx.x, t = threadIdx.x;
    int cnt = min(gcs[b * 16], CAP);
    size_t base = (size_t)b * CAP;

    lh[t] = 0;
    __syncthreads();
    for (int i = t; i < cnt; i += 256)
        atomicAdd(&lh[sregion[base + i] & 255], 1);
    __syncthreads();
    int node = b * 256 + t;
    if (node < NN) cs[node] = lh[t];
}

__global__ void dinv_kernel(const int* __restrict__ cs, float* __restrict__ dinv,
                            float* __restrict__ ndsq, float* __restrict__ sdeg) {
    int i = blockIdx.x * 256 + threadIdx.x;
    if (i < NN) {
        int d = cs[i];
        float di = (d > 0) ? rsqrtf((float)d) : 0.0f;
        dinv[i] = di;
        ndsq[i] = -di * di;
        sdeg[i] = (d > 0) ? sqrtf((float)d) : 0.0f;
    }
}

// ================================================================ weight folding
__global__ void fold_kernel(const float* __restrict__ W, const float* __restrict__ bc,
                            const float* __restrict__ g, const float* __restrict__ be,
                            const float* __restrict__ rm, const float* __restrict__ rv,
                            float* __restrict__ Wf, float* __restrict__ biasf) {
    int idx = blockIdx.x * 256 + threadIdx.x;
    if (idx >= 4096) return;
    int h = idx & 63;
    float sc = g[h] * rsqrtf(rv[h] + BN_EPS);
    float w0 = W[idx], w1 = W[4096 + idx], w2 = W[8192 + idx], w3 = W[12288 + idx];
    Wf[idx]         = (w0 - w2) * sc;
    Wf[4096 + idx]  = (w1 - 3.0f * w3) * sc;
    Wf[8192 + idx]  = (2.0f * w2) * sc;
    Wf[12288 + idx] = (4.0f * w3) * sc;
    if (idx < 64)
        biasf[idx] = (bc[idx] - rm[idx]) * g[idx] * rsqrtf(rv[idx] + BN_EPS) + be[idx];
}

// ================================================================ P0 = bf16(dinv * x)
__global__ void scale0_kernel(const float* __restrict__ x, const float* __restrict__ dinv,
                              u16* __restrict__ P0) {
    int idx = blockIdx.x * 256 + threadIdx.x;       // one float4 per thread
    if (idx >= NN * (HD / 4)) return;
    int n = idx >> 4;
    float di = dinv[n];
    float4 v = ((const float4*)x)[idx];
    u16 o[4] = { f2bf(di * v.x), f2bf(di * v.y), f2bf(di * v.z), f2bf(di * v.w) };
    *(u64*)(&P0[(size_t)idx * 4]) = *(u64*)o;
}

// ================================================================ propagation (round-5 form)
__global__ __launch_bounds__(256) void prop_kernel(
        const u16* __restrict__ Pin, u16* __restrict__ Pout,
        const int* __restrict__ rstart, const int* __restrict__ deg,
        const int* __restrict__ col, const float* __restrict__ ndsq) {
    int d = blockIdx.x * 4 + (threadIdx.x >> 6);
    if (d >= NN) return;
    int lane = threadIdx.x & 63;
    int g = lane >> 4;        // 0..3  edge slot
    int l = lane & 15;        // 0..15 feature quad
    int e0 = rstart[d], e1 = e0 + deg[d];

    float a0 = 0.f, a1 = 0.f, a2 = 0.f, a3 = 0.f;
    int e = e0 + g;
    for (; e + 4 < e1; e += 8) {
        int s0 = col[e], s1 = col[e + 4];
        uint2 u0 = *(const uint2*)(Pin + (size_t)s0 * HD + l * 4);
        uint2 u1 = *(const uint2*)(Pin + (size_t)s1 * HD + l * 4);
        a0 += bflo(u0.x); a1 += bfhi(u0.x);
        a2 += bflo(u0.y); a3 += bfhi(u0.y);
        a0 += bflo(u1.x); a1 += bfhi(u1.x);
        a2 += bflo(u1.y); a3 += bfhi(u1.y);
    }
    if (e < e1) {
        int s = col[e];
        uint2 u = *(const uint2*)(Pin + (size_t)s * HD + l * 4);
        a0 += bflo(u.x); a1 += bfhi(u.x);
        a2 += bflo(u.y); a3 += bfhi(u.y);
    }
    a0 += __shfl_xor(a0, 16); a1 += __shfl_xor(a1, 16);
    a2 += __shfl_xor(a2, 16); a3 += __shfl_xor(a3, 16);
    a0 += __shfl_xor(a0, 32); a1 += __shfl_xor(a1, 32);
    a2 += __shfl_xor(a2, 32); a3 += __shfl_xor(a3, 32);

    if (g == 0) {
        float nd = ndsq[d];
        uint2 o;
        o.x = (unsigned int)f2bf(nd * a0) | ((unsigned int)f2bf(nd * a1) << 16);
        o.y = (unsigned int)f2bf(nd * a2) | ((unsigned int)f2bf(nd * a3) << 16);
        *(uint2*)(Pout + (size_t)d * HD + l * 4) = o;
    }
}

// ================================================================ combine (round-5 form)
template<bool FUSE_HEAD>
__global__ __launch_bounds__(256, 4) void combine_kernel(
        const float* __restrict__ X,      // N x 64 fp32 (T0)
        const u16* __restrict__ P1, const u16* __restrict__ P2,
        const u16* __restrict__ P3,
        const float* __restrict__ sdeg, const float* __restrict__ dinv,
        const float* __restrict__ Wf, const float* __restrict__ biasf,
        float* __restrict__ outh, u16* __restrict__ outP,
        const float* __restrict__ headW, const float* __restrict__ headB,
        float* __restrict__ out16) {
    __shared__ float Tl[64][68];   // +4 pad
    __shared__ float Wl[4096];

    int nbase = blockIdx.x * 64;
    int t = threadIdx.x;
    int h0 = (t & 15) * 4;
    int n0 = (t >> 4) * 4;

    float acc[4][4] = {{0.f}};
    const u16* Ps[3] = {P1, P2, P3};

    for (int k = 0; k < 4; ++k) {
        __syncthreads();   // protect previous iteration's LDS reads
        const float* Wk = Wf + k * 4096;
        #pragma unroll
        for (int j = 0; j < 4; ++j)
            ((float4*)Wl)[t + j * 256] = ((const float4*)Wk)[t + j * 256];

        if (k == 0) {
            const float* Tk = X + (size_t)nbase * HD;
            #pragma unroll
            for (int jj = 0; jj < 4; ++jj) {
                int j = t + jj * 256;
                int r = j >> 4, c = (j & 15) * 4;
                float4 tv = make_float4(0.f, 0.f, 0.f, 0.f);
                if (nbase + r < NN) tv = *(const float4*)(Tk + r * HD + c);
                *(float4*)(&Tl[r][c]) = tv;
            }
        } else {
            const u16* Pk = Ps[k - 1];
            #pragma unroll
            for (int jj = 0; jj < 2; ++jj) {
                int j = t + jj * 256;           // 512 x uint4 (8 bf16 each)
                int r = j >> 3, c0 = (j & 7) * 8;
                int n = nbase + r;
                uint4 u = make_uint4(0, 0, 0, 0);
                float sd = 0.f;
                if (n < NN) {
                    u = *(const uint4*)(Pk + (size_t)n * HD + c0);
                    sd = sdeg[n];
                }
                float* tr = &Tl[r][c0];
                tr[0] = sd * bflo(u.x); tr[1] = sd * bfhi(u.x);
                tr[2] = sd * bflo(u.y); tr[3] = sd * bfhi(u.y);
                tr[4] = sd * bflo(u.z); tr[5] = sd * bfhi(u.z);
                tr[6] = sd * bflo(u.w); tr[7] = sd * bfhi(u.w);
            }
        }
        __syncthreads();

        #pragma unroll 4
        for (int i0 = 0; i0 < 64; i0 += 4) {
            float av[4][4], bv[4][4];
            #pragma unroll
            for (int j = 0; j < 4; ++j) {
                float4 a = *(const float4*)(&Tl[n0 + j][i0]);
                av[j][0] = a.x; av[j][1] = a.y; av[j][2] = a.z; av[j][3] = a.w;
            }
            #pragma unroll
            for (int p = 0; p < 4; ++p) {
                float4 b = *(const float4*)(&Wl[(i0 + p) * 64 + h0]);
                bv[p][0] = b.x; bv[p][1] = b.y; bv[p][2] = b.z; bv[p][3] = b.w;
            }
            #pragma unroll
            for (int j = 0; j < 4; ++j)
                #pragma unroll
                for (int q = 0; q < 4; ++q)
                    #pragma unroll
                    for (int p = 0; p < 4; ++p)
                        acc[j][q] = fmaf(av[j][p], bv[p][q], acc[j][q]);
        }
    }

    float bih[4];
    #pragma unroll
    for (int q = 0; q < 4; ++q) bih[q] = biasf[h0 + q];

    if (!FUSE_HEAD) {
        #pragma unroll
        for (int j = 0; j < 4; ++j) {
            int n = nbase + n0 + j;
            if (n >= NN) continue;
            float4 o;
            o.x = fmaxf(acc[j][0] + bih[0], 0.f);
            o.y = fmaxf(acc[j][1] + bih[1], 0.f);
            o.z = fmaxf(acc[j][2] + bih[2], 0.f);
            o.w = fmaxf(acc[j][3] + bih[3], 0.f);
            *(float4*)(&outh[(size_t)n * HD + h0]) = o;
            float di = dinv[n];
            u16 op[4] = { f2bf(di * o.x), f2bf(di * o.y), f2bf(di * o.z), f2bf(di * o.w) };
            *(u64*)(&outP[(size_t)n * HD + h0]) = *(u64*)op;
        }
    } else {
        __syncthreads();   // done reading Tl for k=3
        #pragma unroll
        for (int j = 0; j < 4; ++j) {
            float4 o;
            o.x = fmaxf(acc[j][0] + bih[0], 0.f);
            o.y = fmaxf(acc[j][1] + bih[1], 0.f);
            o.z = fmaxf(acc[j][2] + bih[2], 0.f);
            o.w = fmaxf(acc[j][3] + bih[3], 0.f);
            *(float4*)(&Tl[n0 + j][h0]) = o;
        }
        ((float4*)Wl)[t] = ((const float4*)headW)[t & 255];  // 64x16 = 256 float4
        __syncthreads();

        int n = t >> 2;
        int oc0 = (t & 3) * 4;
        float4 o;
        o.x = headB[oc0]; o.y = headB[oc0 + 1]; o.z = headB[oc0 + 2]; o.w = headB[oc0 + 3];
        #pragma unroll 8
        for (int i = 0; i < 64; ++i) {
            float tv = Tl[n][i];
            const float* wr = &Wl[i * OCD + oc0];
            o.x = fmaf(tv, wr[0], o.x);
            o.y = fmaf(tv, wr[1], o.y);
            o.z = fmaf(tv, wr[2], o.z);
            o.w = fmaf(tv, wr[3], o.w);
        }
        int nn = nbase + n;
        if (nn < NN) *(float4*)(&out16[(size_t)nn * OCD + oc0]) = o;
    }
}

// ================================================================ launch
static inline size_t al256(size_t x) { return (x + 255) & ~(size_t)255; }

extern "C" void kernel_launch(void* const* d_in, const int* in_sizes, int n_in,
                              void* d_out, int out_size, void* d_ws, size_t ws_size,
                              hipStream_t stream) {
    const float* x     = (const float*)d_in[0];
    const int*   ei    = (const int*)  d_in[1];
    const float* W1    = (const float*)d_in[2];
    const float* bc1   = (const float*)d_in[3];
    const float* W2    = (const float*)d_in[4];
    const float* bc2   = (const float*)d_in[5];
    const float* W3    = (const float*)d_in[6];
    const float* bc3   = (const float*)d_in[7];
    const float* g1  = (const float*)d_in[8],  *be1 = (const float*)d_in[9];
    const float* rm1 = (const float*)d_in[10], *rv1 = (const float*)d_in[11];
    const float* g2  = (const float*)d_in[12], *be2 = (const float*)d_in[13];
    const float* rm2 = (const float*)d_in[14], *rv2 = (const float*)d_in[15];
    const float* g3  = (const float*)d_in[16], *be3 = (const float*)d_in[17];
    const float* rm3 = (const float*)d_in[18], *rv3 = (const float*)d_in[19];
    const float* headW = (const float*)d_in[20];
    const float* headB = (const float*)d_in[21];

    const int* src = ei;
    const int* dst = ei + EE;

    char* w = (char*)d_ws;
    size_t off = 0;
    auto take = [&](size_t bytes) { char* p = w + off; off += al256(bytes); return p; };
    float* dinv   = (float*)take(NN * 4);
    float* ndsq   = (float*)take(NN * 4);
    float* sdeg   = (float*)take(NN * 4);
    int*   cs     = (int*)  take(NN * 4);
    int*   deg    = (int*)  take(NN * 4);
    int*   rstart = (int*)  take(NN * 4);
    int*   gc     = (int*)  take(2 * NBUCK * 16 * 4);        // gcd | gcs contiguous
    int*   gcd    = gc;
    int*   gcs    = gc + NBUCK * 16;
    u64*   bregion= (u64*)  take((size_t)NBUCK * CAP * 8);   // 16.0 MB
    int*   sregion= (int*)  take((size_t)NBUCK * CAP * 4);   //  8.0 MB
    int*   colp   = (int*)  take((size_t)NBUCK * CAP * 4);   //  8.0 MB
    float* Wf1    = (float*)take(16384 * 4);
    float* Wf2    = (float*)take(16384 * 4);
    float* Wf3    = (float*)take(16384 * 4);
    float* bf1    = (float*)take(64 * 4);
    float* bf2    = (float*)take(64 * 4);
    float* bf3    = (float*)take(64 * 4);
    const size_t NH = (size_t)NN * HD;
    u16* P0 = (u16*)take(NH * 2);
    u16* P1 = (u16*)take(NH * 2);
    u16* P2 = (u16*)take(NH * 2);
    u16* P3 = (u16*)take(NH * 2);
    float* D = (float*)take(NH * 4);

    const int AB = (EE + 4095) / 4096;          // 391 bucketing blocks
    const int NG = (NN + 255) / 256;
    const int PROP_GRID = (NN + 3) / 4;
    const int CB_GRID   = (NN + 63) / 64;
    const int S0_GRID   = (NN * (HD / 4) + 255) / 256;

    // ---- CSR build via two-level bucketing
    hipMemsetAsync(gc, 0, 2 * NBUCK * 16 * 4, stream);
    bucketA_kernel <<<AB, 256, 0, stream>>>(src, dst, gcd, bregion);
    bucketA2_kernel<<<AB, 256, 0, stream>>>(src, gcs, sregion);
    bucketB_kernel <<<NBUCK, 256, 0, stream>>>(gcd, bregion, rstart, deg, colp);
    bucketB2_kernel<<<NBUCK, 256, 0, stream>>>(gcs, sregion, cs);
    dinv_kernel<<<NG, 256, 0, stream>>>(cs, dinv, ndsq, sdeg);
    fold_kernel<<<16, 256, 0, stream>>>(W1, bc1, g1, be1, rm1, rv1, Wf1, bf1);
    fold_kernel<<<16, 256, 0, stream>>>(W2, bc2, g2, be2, rm2, rv2, Wf2, bf2);
    fold_kernel<<<16, 256, 0, stream>>>(W3, bc3, g3, be3, rm3, rv3, Wf3, bf3);
    scale0_kernel<<<S0_GRID, 256, 0, stream>>>(x, dinv, P0);

    float* out16 = (float*)d_out;

    // ---- layer 1
    prop_kernel<<<PROP_GRID, 256, 0, stream>>>(P0, P1, rstart, deg, colp, ndsq);
    prop_kernel<<<PROP_GRID, 256, 0, stream>>>(P1, P2, rstart, deg, colp, ndsq);
    prop_kernel<<<PROP_GRID, 256, 0, stream>>>(P2, P3, rstart, deg, colp, ndsq);
    combine_kernel<false><<<CB_GRID, 256, 0, stream>>>(x, P1, P2, P3, sdeg, dinv,
                                                       Wf1, bf1, D, P0,
                                                       nullptr, nullptr, nullptr);
    // ---- layer 2
    prop_kernel<<<PROP_GRID, 256, 0, stream>>>(P0, P1, rstart, deg, colp, ndsq);
    prop_kernel<<<PROP_GRID, 256, 0, stream>>>(P1, P2, rstart, deg, colp, ndsq);
    prop_kernel<<<PROP_GRID, 256, 0, stream>>>(P2, P3, rstart, deg, colp, ndsq);
    combine_kernel<false><<<CB_GRID, 256, 0, stream>>>(D, P1, P2, P3, sdeg, dinv,
                                                       Wf2, bf2, D, P0,
                                                       nullptr, nullptr, nullptr);
    // ---- layer 3 (head fused)
    prop_kernel<<<PROP_GRID, 256, 0, stream>>>(P0, P1, rstart, deg, colp, ndsq);
    prop_kernel<<<PROP_GRID, 256, 0, stream>>>(P1, P2, rstart, deg, colp, ndsq);
    prop_kernel<<<PROP_GRID, 256, 0, stream>>>(P2, P3, rstart, deg, colp, ndsq);
    combine_kernel<true><<<CB_GRID, 256, 0, stream>>>(D, P1, P2, P3, sdeg, dinv,
                                                      Wf3, bf3, nullptr, nullptr,
                                                      headW, headB, out16);
}

// Round 10
// 622.170 us; speedup vs baseline: 2.6030x; 1.0805x over previous
//
#include <hip/hip_runtime.h>

#define NN 100000
#define EE 1600000
#define HD 64
#define OCD 16
#define NBUCK 391          // ceil(NN/256)
#define CAP 5120           // per-bucket edge capacity
#define BN_EPS 1e-5f

typedef unsigned short u16;
typedef unsigned long long u64;
typedef __attribute__((ext_vector_type(8))) short short8v;  // 8 bf16 (4 VGPR)
typedef __attribute__((ext_vector_type(4))) float f32x4;

union f32u32 { float f; unsigned int u; };

__device__ __forceinline__ float bflo(unsigned int u) {
    f32u32 c; c.u = u << 16; return c.f;
}
__device__ __forceinline__ float bfhi(unsigned int u) {
    f32u32 c; c.u = u & 0xffff0000u; return c.f;
}
__device__ __forceinline__ float bf2f(u16 u) {
    f32u32 c; c.u = (unsigned int)u << 16; return c.f;
}
__device__ __forceinline__ u16 f2bf(float f) {
    f32u32 c; c.f = f;
    unsigned int r = 0x7fffu + ((c.u >> 16) & 1u);   // RNE
    return (u16)((c.u + r) >> 16);
}

// ================================================================ bucket pass A (dst)
__global__ __launch_bounds__(256) void bucketA_kernel(
        const int* __restrict__ src, const int* __restrict__ dst,
        int* __restrict__ gcd, u64* __restrict__ bregion) {
    __shared__ int lh[NBUCK], lbase[NBUCK], lcur[NBUCK];
    int t = threadIdx.x;
    int ebase = blockIdx.x * 4096;

    for (int i = t; i < NBUCK; i += 256) lh[i] = 0;
    __syncthreads();

    int es[16], ed[16];
    #pragma unroll
    for (int j = 0; j < 16; ++j) {
        int e = ebase + j * 256 + t;
        if (e < EE) {
            es[j] = src[e]; ed[j] = dst[e];
            atomicAdd(&lh[ed[j] >> 8], 1);
        } else { es[j] = -1; ed[j] = 0; }
    }
    __syncthreads();
    for (int i = t; i < NBUCK; i += 256) {
        int c = lh[i];
        lbase[i] = (c > 0) ? atomicAdd(&gcd[i * 16], c) : 0;
        lcur[i] = 0;
    }
    __syncthreads();
    #pragma unroll
    for (int j = 0; j < 16; ++j) {
        if (es[j] >= 0) {
            int b = ed[j] >> 8;
            int r = atomicAdd(&lcur[b], 1);
            int pos = lbase[b] + r;
            if (pos < CAP)
                bregion[(size_t)b * CAP + pos] =
                    (u64)(unsigned int)es[j] | ((u64)(unsigned int)ed[j] << 32);
        }
    }
}

// bucket pass A2 (src, for out-degree)
__global__ __launch_bounds__(256) void bucketA2_kernel(
        const int* __restrict__ src,
        int* __restrict__ gcs, int* __restrict__ sregion) {
    __shared__ int lh[NBUCK], lbase[NBUCK], lcur[NBUCK];
    int t = threadIdx.x;
    int ebase = blockIdx.x * 4096;

    for (int i = t; i < NBUCK; i += 256) lh[i] = 0;
    __syncthreads();

    int es[16];
    #pragma unroll
    for (int j = 0; j < 16; ++j) {
        int e = ebase + j * 256 + t;
        if (e < EE) {
            es[j] = src[e];
            atomicAdd(&lh[es[j] >> 8], 1);
        } else es[j] = -1;
    }
    __syncthreads();
    for (int i = t; i < NBUCK; i += 256) {
        int c = lh[i];
        lbase[i] = (c > 0) ? atomicAdd(&gcs[i * 16], c) : 0;
        lcur[i] = 0;
    }
    __syncthreads();
    #pragma unroll
    for (int j = 0; j < 16; ++j) {
        if (es[j] >= 0) {
            int b = es[j] >> 8;
            int r = atomicAdd(&lcur[b], 1);
            int pos = lbase[b] + r;
            if (pos < CAP)
                sregion[(size_t)b * CAP + pos] = es[j];
        }
    }
}

// pass B: per dst-bucket CSR
__global__ __launch_bounds__(256) void bucketB_kernel(
        const int* __restrict__ gcd, const u64* __restrict__ bregion,
        int* __restrict__ rstart, int* __restrict__ deg,
        int* __restrict__ colp) {
    __shared__ int lh[256], lsc[256], lcur[256];
    int b = blockIdx.x, t = threadIdx.x;
    int cnt = min(gcd[b * 16], CAP);
    size_t base = (size_t)b * CAP;

    lh[t] = 0;
    __syncthreads();
    for (int i = t; i < cnt; i += 256) {
        int d = (int)(bregion[base + i] >> 32);
        atomicAdd(&lh[d & 255], 1);
    }
    __syncthreads();
    lsc[t] = lh[t];
    __syncthreads();
    for (int o = 1; o < 256; o <<= 1) {
        int v = (t >= o) ? lsc[t - o] : 0;
        __syncthreads();
        lsc[t] += v;
        __syncthreads();
    }
    int excl = lsc[t] - lh[t];
    int node = b * 256 + t;
    if (node < NN) {
        rstart[node] = (int)base + excl;
        deg[node] = lh[t];
    }
    lcur[t] = excl;
    __syncthreads();
    for (int i = t; i < cnt; i += 256) {
        u64 pair = bregion[base + i];
        int s = (int)(unsigned int)(pair & 0xffffffffu);
        int dl = ((int)(pair >> 32)) & 255;
        int p = atomicAdd(&lcur[dl], 1);
        colp[base + p] = s;
    }
}

// per src-bucket: out-degree -> cs
__global__ __launch_bounds__(256) void bucketB2_kernel(
        const int* __restrict__ gcs, const int* __restrict__ sregion,
        int* __restrict__ cs) {
    __shared__ int lh[256];
    int b = blockIdx.x, t = threadIdx.x;
    int cnt = min(gcs[b * 16], CAP);
    size_t base = (size_t)b * CAP;

    lh[t] = 0;
    __syncthreads();
    for (int i = t; i < cnt; i += 256)
        atomicAdd(&lh[sregion[base + i] & 255], 1);
    __syncthreads();
    int node = b * 256 + t;
    if (node < NN) cs[node] = lh[t];
}

__global__ void dinv_kernel(const int* __restrict__ cs, float* __restrict__ dinv,
                            float* __restrict__ ndsq, float* __restrict__ sdeg) {
    int i = blockIdx.x * 256 + threadIdx.x;
    if (i < NN) {
        int d = cs[i];
        float di = (d > 0) ? rsqrtf((float)d) : 0.0f;
        dinv[i] = di;
        ndsq[i] = -di * di;
        sdeg[i] = (d > 0) ? sqrtf((float)d) : 0.0f;
    }
}

// ================================================================ weight fold + MFMA-fragment repack
// W'0=(W0-W2)sc  W'1=(W1-3W3)sc  W'2=2W2·sc  W'3=4W3·sc ; split hi/lo bf16.
// Frag layout: Wfrag[(km*2+hl)*4096 + ks*2048 + nt*512 + lane*8 + j]
//   where k-dim index i = ks*32 + (lane>>4)*8 + j, h = nt*16 + (lane&15).
__global__ void fold_kernel(const float* __restrict__ W, const float* __restrict__ bc,
                            const float* __restrict__ g, const float* __restrict__ be,
                            const float* __restrict__ rm, const float* __restrict__ rv,
                            u16* __restrict__ Wfrag, float* __restrict__ biasf) {
    int idx = blockIdx.x * 256 + threadIdx.x;
    if (idx >= 16384) return;
    int km = idx >> 12, r = idx & 4095, i = r >> 6, h = r & 63;
    float sc = g[h] * rsqrtf(rv[h] + BN_EPS);
    int e = i * 64 + h;
    float wv;
    if      (km == 0) wv = (W[e] - W[8192 + e]) * sc;
    else if (km == 1) wv = (W[4096 + e] - 3.0f * W[12288 + e]) * sc;
    else if (km == 2) wv = 2.0f * W[8192 + e] * sc;
    else              wv = 4.0f * W[12288 + e] * sc;
    u16 hi = f2bf(wv);
    u16 lo = f2bf(wv - bf2f(hi));
    int lane = (((i & 31) >> 3) << 4) | (h & 15);
    int base = (km * 2) * 4096 + (i >> 5) * 2048 + (h >> 4) * 512 + lane * 8 + (i & 7);
    Wfrag[base] = hi;
    Wfrag[base + 4096] = lo;
    if (idx < 64)
        biasf[idx] = (bc[idx] - rm[idx]) * g[idx] * rsqrtf(rv[idx] + BN_EPS) + be[idx];
}

// ================================================================ x -> Xhi/Xlo (split bf16) + P0 = bf16(dinv*x)
__global__ void scale0_kernel(const float* __restrict__ x, const float* __restrict__ dinv,
                              u16* __restrict__ Xhi, u16* __restrict__ Xlo,
                              u16* __restrict__ P0) {
    int idx = blockIdx.x * 256 + threadIdx.x;       // one float4 per thread
    if (idx >= NN * (HD / 4)) return;
    int n = idx >> 4;
    float di = dinv[n];
    float4 v = ((const float4*)x)[idx];
    float vv[4] = {v.x, v.y, v.z, v.w};
    u16 hi[4], lo[4], p[4];
    #pragma unroll
    for (int j = 0; j < 4; ++j) {
        hi[j] = f2bf(vv[j]);
        lo[j] = f2bf(vv[j] - bf2f(hi[j]));
        p[j]  = f2bf(di * vv[j]);
    }
    *(u64*)(&Xhi[(size_t)idx * 4]) = *(u64*)hi;
    *(u64*)(&Xlo[(size_t)idx * 4]) = *(u64*)lo;
    *(u64*)(&P0 [(size_t)idx * 4]) = *(u64*)p;
}

// ================================================================ propagation (round-5 form, unchanged)
__global__ __launch_bounds__(256) void prop_kernel(
        const u16* __restrict__ Pin, u16* __restrict__ Pout,
        const int* __restrict__ rstart, const int* __restrict__ deg,
        const int* __restrict__ col, const float* __restrict__ ndsq) {
    int d = blockIdx.x * 4 + (threadIdx.x >> 6);
    if (d >= NN) return;
    int lane = threadIdx.x & 63;
    int g = lane >> 4;        // 0..3  edge slot
    int l = lane & 15;        // 0..15 feature quad
    int e0 = rstart[d], e1 = e0 + deg[d];

    float a0 = 0.f, a1 = 0.f, a2 = 0.f, a3 = 0.f;
    int e = e0 + g;
    for (; e + 4 < e1; e += 8) {
        int s0 = col[e], s1 = col[e + 4];
        uint2 u0 = *(const uint2*)(Pin + (size_t)s0 * HD + l * 4);
        uint2 u1 = *(const uint2*)(Pin + (size_t)s1 * HD + l * 4);
        a0 += bflo(u0.x); a1 += bfhi(u0.x);
        a2 += bflo(u0.y); a3 += bfhi(u0.y);
        a0 += bflo(u1.x); a1 += bfhi(u1.x);
        a2 += bflo(u1.y); a3 += bfhi(u1.y);
    }
    if (e < e1) {
        int s = col[e];
        uint2 u = *(const uint2*)(Pin + (size_t)s * HD + l * 4);
        a0 += bflo(u.x); a1 += bfhi(u.x);
        a2 += bflo(u.y); a3 += bfhi(u.y);
    }
    a0 += __shfl_xor(a0, 16); a1 += __shfl_xor(a1, 16);
    a2 += __shfl_xor(a2, 16); a3 += __shfl_xor(a3, 16);
    a0 += __shfl_xor(a0, 32); a1 += __shfl_xor(a1, 32);
    a2 += __shfl_xor(a2, 32); a3 += __shfl_xor(a3, 32);

    if (g == 0) {
        float nd = ndsq[d];
        uint2 o;
        o.x = (unsigned int)f2bf(nd * a0) | ((unsigned int)f2bf(nd * a1) << 16);
        o.y = (unsigned int)f2bf(nd * a2) | ((unsigned int)f2bf(nd * a3) << 16);
        *(uint2*)(Pout + (size_t)d * HD + l * 4) = o;
    }
}

// ================================================================ MFMA combine
// acc = (Xhi+Xlo)@W0' + sdeg ⊙ Σ_{k≥1} P_k@Wk' ; h = relu(acc + biasf)
// Block = 64 nodes; wave w = 16-node m-tile; 4 n-tiles of 16 h each.
template<bool FUSE_HEAD>
__global__ __launch_bounds__(256) void combine_kernel(
        const u16* __restrict__ Xhi, const u16* __restrict__ Xlo,
        const u16* __restrict__ P1, const u16* __restrict__ P2,
        const u16* __restrict__ P3,
        const float* __restrict__ sdeg, const float* __restrict__ dinv,
        const u16* __restrict__ Wfrag, const float* __restrict__ biasf,
        u16* __restrict__ outDhi, u16* __restrict__ outDlo, u16* __restrict__ outP0,
        const float* __restrict__ headW, const float* __restrict__ headB,
        float* __restrict__ out16) {
    int t = threadIdx.x;
    int w = t >> 6;           // m-tile
    int l = t & 63;
    int nbase = blockIdx.x * 64;

    int arow = nbase + w * 16 + (l & 15);
    if (arow > NN - 1) arow = NN - 1;            // tail clamp (stores guarded)
    size_t abase = (size_t)arow * HD;

    f32x4 accX[4], accP[4];
    #pragma unroll
    for (int nt = 0; nt < 4; ++nt) {
        accX[nt] = (f32x4){0.f, 0.f, 0.f, 0.f};
        accP[nt] = (f32x4){0.f, 0.f, 0.f, 0.f};
    }

    #pragma unroll
    for (int ks = 0; ks < 2; ++ks) {
        size_t ao = abase + ks * 32 + (l >> 4) * 8;
        short8v aXhi = *(const short8v*)(Xhi + ao);
        short8v aXlo = *(const short8v*)(Xlo + ao);
        short8v aP1  = *(const short8v*)(P1  + ao);
        short8v aP2  = *(const short8v*)(P2  + ao);
        short8v aP3  = *(const short8v*)(P3  + ao);
        #pragma unroll
        for (int nt = 0; nt < 4; ++nt) {
            const u16* wb = Wfrag + ks * 2048 + nt * 512 + l * 8;
            short8v b0h = *(const short8v*)(wb);            // km0 hi
            short8v b0l = *(const short8v*)(wb + 4096);     // km0 lo
            short8v b1h = *(const short8v*)(wb + 8192);
            short8v b1l = *(const short8v*)(wb + 12288);
            short8v b2h = *(const short8v*)(wb + 16384);
            short8v b2l = *(const short8v*)(wb + 20480);
            short8v b3h = *(const short8v*)(wb + 24576);
            short8v b3l = *(const short8v*)(wb + 28672);
            accX[nt] = __builtin_amdgcn_mfma_f32_16x16x32_bf16(aXhi, b0h, accX[nt], 0, 0, 0);
            accX[nt] = __builtin_amdgcn_mfma_f32_16x16x32_bf16(aXlo, b0h, accX[nt], 0, 0, 0);
            accX[nt] = __builtin_amdgcn_mfma_f32_16x16x32_bf16(aXhi, b0l, accX[nt], 0, 0, 0);
            accP[nt] = __builtin_amdgcn_mfma_f32_16x16x32_bf16(aP1,  b1h, accP[nt], 0, 0, 0);
            accP[nt] = __builtin_amdgcn_mfma_f32_16x16x32_bf16(aP1,  b1l, accP[nt], 0, 0, 0);
            accP[nt] = __builtin_amdgcn_mfma_f32_16x16x32_bf16(aP2,  b2h, accP[nt], 0, 0, 0);
            accP[nt] = __builtin_amdgcn_mfma_f32_16x16x32_bf16(aP2,  b2l, accP[nt], 0, 0, 0);
            accP[nt] = __builtin_amdgcn_mfma_f32_16x16x32_bf16(aP3,  b3h, accP[nt], 0, 0, 0);
            accP[nt] = __builtin_amdgcn_mfma_f32_16x16x32_bf16(aP3,  b3l, accP[nt], 0, 0, 0);
        }
    }

    // epilogue: C/D layout col=lane&15, row=(lane>>4)*4+reg  [m89 verified]
    int col = l & 15;
    int rbase = w * 16 + (l >> 4) * 4;

    if (!FUSE_HEAD) {
        #pragma unroll
        for (int nt = 0; nt < 4; ++nt) {
            int h = nt * 16 + col;
            float bi = biasf[h];
            #pragma unroll
            for (int reg = 0; reg < 4; ++reg) {
                int node = nbase + rbase + reg;
                int nodeL = node > NN - 1 ? NN - 1 : node;
                float val = accX[nt][reg] + sdeg[nodeL] * accP[nt][reg] + bi;
                val = fmaxf(val, 0.f);
                if (node < NN) {
                    u16 hi = f2bf(val);
                    size_t o = (size_t)node * HD + h;
                    outDhi[o] = hi;
                    outDlo[o] = f2bf(val - bf2f(hi));
                    outP0[o]  = f2bf(dinv[nodeL] * val);
                }
            }
        }
    } else {
        __shared__ float Tl[64][68];
        __shared__ float Wl[HD * OCD];
        #pragma unroll
        for (int nt = 0; nt < 4; ++nt) {
            int h = nt * 16 + col;
            float bi = biasf[h];
            #pragma unroll
            for (int reg = 0; reg < 4; ++reg) {
                int node = nbase + rbase + reg;
                int nodeL = node > NN - 1 ? NN - 1 : node;
                float val = accX[nt][reg] + sdeg[nodeL] * accP[nt][reg] + bi;
                Tl[rbase + reg][h] = fmaxf(val, 0.f);
            }
        }
        ((float4*)Wl)[t & 255] = ((const float4*)headW)[t & 255];  // 1024 floats
        __syncthreads();

        int n = t >> 2;
        int oc0 = (t & 3) * 4;
        float4 o;
        o.x = headB[oc0]; o.y = headB[oc0 + 1]; o.z = headB[oc0 + 2]; o.w = headB[oc0 + 3];
        #pragma unroll 8
        for (int i = 0; i < 64; ++i) {
            float tv = Tl[n][i];
            const float* wr = &Wl[i * OCD + oc0];
            o.x = fmaf(tv, wr[0], o.x);
            o.y = fmaf(tv, wr[1], o.y);
            o.z = fmaf(tv, wr[2], o.z);
            o.w = fmaf(tv, wr[3], o.w);
        }
        int nn = nbase + n;
        if (nn < NN) *(float4*)(&out16[(size_t)nn * OCD + oc0]) = o;
    }
}

// ================================================================ launch
static inline size_t al256(size_t x) { return (x + 255) & ~(size_t)255; }

extern "C" void kernel_launch(void* const* d_in, const int* in_sizes, int n_in,
                              void* d_out, int out_size, void* d_ws, size_t ws_size,
                              hipStream_t stream) {
    const float* x     = (const float*)d_in[0];
    const int*   ei    = (const int*)  d_in[1];
    const float* W1    = (const float*)d_in[2];
    const float* bc1   = (const float*)d_in[3];
    const float* W2    = (const float*)d_in[4];
    const float* bc2   = (const float*)d_in[5];
    const float* W3    = (const float*)d_in[6];
    const float* bc3   = (const float*)d_in[7];
    const float* g1  = (const float*)d_in[8],  *be1 = (const float*)d_in[9];
    const float* rm1 = (const float*)d_in[10], *rv1 = (const float*)d_in[11];
    const float* g2  = (const float*)d_in[12], *be2 = (const float*)d_in[13];
    const float* rm2 = (const float*)d_in[14], *rv2 = (const float*)d_in[15];
    const float* g3  = (const float*)d_in[16], *be3 = (const float*)d_in[17];
    const float* rm3 = (const float*)d_in[18], *rv3 = (const float*)d_in[19];
    const float* headW = (const float*)d_in[20];
    const float* headB = (const float*)d_in[21];

    const int* src = ei;
    const int* dst = ei + EE;

    char* w = (char*)d_ws;
    size_t off = 0;
    auto take = [&](size_t bytes) { char* p = w + off; off += al256(bytes); return p; };
    float* dinv   = (float*)take(NN * 4);
    float* ndsq   = (float*)take(NN * 4);
    float* sdeg   = (float*)take(NN * 4);
    int*   cs     = (int*)  take(NN * 4);
    int*   deg    = (int*)  take(NN * 4);
    int*   rstart = (int*)  take(NN * 4);
    int*   gc     = (int*)  take(2 * NBUCK * 16 * 4);        // gcd | gcs contiguous
    int*   gcd    = gc;
    int*   gcs    = gc + NBUCK * 16;
    u64*   bregion= (u64*)  take((size_t)NBUCK * CAP * 8);   // 16.0 MB
    int*   sregion= (int*)  take((size_t)NBUCK * CAP * 4);   //  8.0 MB
    int*   colp   = (int*)  take((size_t)NBUCK * CAP * 4);   //  8.0 MB
    u16*   Wfrag1 = (u16*)  take(32768 * 2);                 // 64 KB each
    u16*   Wfrag2 = (u16*)  take(32768 * 2);
    u16*   Wfrag3 = (u16*)  take(32768 * 2);
    float* bf1    = (float*)take(64 * 4);
    float* bf2    = (float*)take(64 * 4);
    float* bf3    = (float*)take(64 * 4);
    const size_t NH = (size_t)NN * HD;
    u16* Xhi = (u16*)take(NH * 2);
    u16* Xlo = (u16*)take(NH * 2);
    u16* Yhi = (u16*)take(NH * 2);
    u16* Ylo = (u16*)take(NH * 2);
    u16* P0  = (u16*)take(NH * 2);
    u16* P1  = (u16*)take(NH * 2);
    u16* P2  = (u16*)take(NH * 2);
    u16* P3  = (u16*)take(NH * 2);

    const int AB = (EE + 4095) / 4096;          // 391 bucketing blocks
    const int NG = (NN + 255) / 256;
    const int PROP_GRID = (NN + 3) / 4;
    const int CB_GRID   = (NN + 63) / 64;
    const int S0_GRID   = (NN * (HD / 4) + 255) / 256;

    // ---- CSR build via two-level bucketing
    hipMemsetAsync(gc, 0, 2 * NBUCK * 16 * 4, stream);
    bucketA_kernel <<<AB, 256, 0, stream>>>(src, dst, gcd, bregion);
    bucketA2_kernel<<<AB, 256, 0, stream>>>(src, gcs, sregion);
    bucketB_kernel <<<NBUCK, 256, 0, stream>>>(gcd, bregion, rstart, deg, colp);
    bucketB2_kernel<<<NBUCK, 256, 0, stream>>>(gcs, sregion, cs);
    dinv_kernel<<<NG, 256, 0, stream>>>(cs, dinv, ndsq, sdeg);
    fold_kernel<<<64, 256, 0, stream>>>(W1, bc1, g1, be1, rm1, rv1, Wfrag1, bf1);
    fold_kernel<<<64, 256, 0, stream>>>(W2, bc2, g2, be2, rm2, rv2, Wfrag2, bf2);
    fold_kernel<<<64, 256, 0, stream>>>(W3, bc3, g3, be3, rm3, rv3, Wfrag3, bf3);
    scale0_kernel<<<S0_GRID, 256, 0, stream>>>(x, dinv, Xhi, Xlo, P0);

    float* out16 = (float*)d_out;

    // ---- layer 1
    prop_kernel<<<PROP_GRID, 256, 0, stream>>>(P0, P1, rstart, deg, colp, ndsq);
    prop_kernel<<<PROP_GRID, 256, 0, stream>>>(P1, P2, rstart, deg, colp, ndsq);
    prop_kernel<<<PROP_GRID, 256, 0, stream>>>(P2, P3, rstart, deg, colp, ndsq);
    combine_kernel<false><<<CB_GRID, 256, 0, stream>>>(
        Xhi, Xlo, P1, P2, P3, sdeg, dinv, Wfrag1, bf1,
        Yhi, Ylo, P0, nullptr, nullptr, nullptr);
    // ---- layer 2
    prop_kernel<<<PROP_GRID, 256, 0, stream>>>(P0, P1, rstart, deg, colp, ndsq);
    prop_kernel<<<PROP_GRID, 256, 0, stream>>>(P1, P2, rstart, deg, colp, ndsq);
    prop_kernel<<<PROP_GRID, 256, 0, stream>>>(P2, P3, rstart, deg, colp, ndsq);
    combine_kernel<false><<<CB_GRID, 256, 0, stream>>>(
        Yhi, Ylo, P1, P2, P3, sdeg, dinv, Wfrag2, bf2,
        Xhi, Xlo, P0, nullptr, nullptr, nullptr);
    // ---- layer 3 (head fused)
    prop_kernel<<<PROP_GRID, 256, 0, stream>>>(P0, P1, rstart, deg, colp, ndsq);
    prop_kernel<<<PROP_GRID, 256, 0, stream>>>(P1, P2, rstart, deg, colp, ndsq);
    prop_kernel<<<PROP_GRID, 256, 0, stream>>>(P2, P3, rstart, deg, colp, ndsq);
    combine_kernel<true><<<CB_GRID, 256, 0, stream>>>(
        Xhi, Xlo, P1, P2, P3, sdeg, dinv, Wfrag3, bf3,
        nullptr, nullptr, nullptr, headW, headB, out16);
}